// Round 1
// baseline (1413.690 us; speedup 1.0000x reference)
//
#include <hip/hip_runtime.h>

// CTC-like forward scan on MI355X.
// T=4096 sequential steps over fwd[B][P+1]; one block per batch element,
// thread p owns position p+1 (own value in register), left neighbor via
// double-buffered LDS, one __syncthreads per step.

#define TT 4096
#define BB 64
#define FF 5
#define PP 512
#define NEG_LARGE -1e30f

__global__ __launch_bounds__(512, 2)
void ctc_fwd_kernel(const float* __restrict__ x,
                    const int* __restrict__ seqs,
                    const int* __restrict__ seqlens,
                    float* __restrict__ out) {
    __shared__ float bufA[PP + 1];
    __shared__ float bufB[PP + 1];

    const int b = blockIdx.x;
    const int p = threadIdx.x;            // handles fwd position p+1
    const int sq = seqs[b * PP + p];      // move-emission feature for position p+1 (constant over t)

    // init fwd: position 0 = 0, rest = NEG_LARGE
    float f  = NEG_LARGE;                 // my fwd[p+1]
    float f0 = 0.0f;                      // thread 0 also tracks fwd[0]
    bufA[p] = (p == 0) ? 0.0f : NEG_LARGE;
    if (p == 0) bufA[PP] = NEG_LARGE;
    __syncthreads();

    const float* __restrict__ xb = x + b * FF;   // row for (t=0, b)
    const int rowstride = BB * FF;               // 320 floats per t

    float* cur = bufA;
    float* nxt = bufB;

    // prefetch t=0 scores (wave-uniform addresses -> L1 broadcast)
    float stay = xb[4];
    float mv   = xb[sq];
    const float* xt = xb + rowstride;            // points at row t+1

    for (int t = 0; t < TT; ++t) {
        // prefetch scores for t+1 (clamp pointer on last iter; value unused)
        const float* xn = (t + 1 < TT) ? xt : xb;
        float stay_n = xn[4];
        float mv_n   = xn[sq];
        xt += rowstride;

        // step: new[p+1] = logaddexp(fwd[p] + mv, fwd[p+1] + stay)
        float left = cur[p];                     // fwd[p] from neighbor
        float a  = f + stay;
        float bb = left + mv;
        float hi = fmaxf(a, bb);
        float d  = -fabsf(a - bb);               // <= 0
        float e  = __expf(d);
        f = hi + __logf(1.0f + e);
        nxt[p + 1] = f;
        if (p == 0) {                            // position 0: pure stay
            f0 += stay;
            nxt[0] = f0;
        }
        __syncthreads();
        float* tmp = cur; cur = nxt; nxt = tmp;
        stay = stay_n; mv = mv_n;
    }

    if (p == 0) {
        int sl = seqlens[b];
        out[b] = -cur[sl] / (float)TT;
    }
}

extern "C" void kernel_launch(void* const* d_in, const int* in_sizes, int n_in,
                              void* d_out, int out_size, void* d_ws, size_t ws_size,
                              hipStream_t stream) {
    const float* x        = (const float*)d_in[0];
    const int*   seqs     = (const int*)d_in[1];
    const int*   seqlens  = (const int*)d_in[2];
    float*       out      = (float*)d_out;

    ctc_fwd_kernel<<<BB, PP, 0, stream>>>(x, seqs, seqlens, out);
}

// Round 4
// 721.601 us; speedup vs baseline: 1.9591x; 1.9591x over previous
//
#include <hip/hip_runtime.h>

// CTC-like forward scan — single wave per batch element, all-register state.
// Lane l owns positions 8l+1..8l+8 (F[0..7]); lane 0 also owns position 0
// (F0, with its own exponent M0). Linear domain: F' = F*S + F_left*V, with
// per-lane power-of-2 offset M (true value = F * 2^M), renormalized every
// 8 steps. Neighbor exchange via __shfl_up (ds_bpermute) + explicit lane-0
// fixup. Per step, the 5 x-values are loaded by lanes 0..4 (one dword load),
// exp'd once, and distributed by ds_bpermute. No LDS ring, no d_ws, no
// cross-wave sync, no __syncthreads in the T loop.

#define TT 4096
#define BB 64
#define PP 512
#define LN2F 0.69314718055994531f

__device__ __forceinline__ void step_fn(int t, int rs, int l,
                                        const float* __restrict__ xbase,
                                        float (&raw)[8], const int (&idx)[8],
                                        float (&F)[8], float& F0, int& M, int& M0,
                                        const float (&Vc)[8], float Sc,
                                        float (&Vn)[8], float& Sn, bool renorm) {
    // --- boundary shuffles first (chain-critical; issue before V-prep ds ops)
    float Fl = __shfl_up(F[7], 1, 64);
    int   Ml = __shfl_up(M, 1, 64);
    if (l == 0) { Fl = F0; Ml = M0; }

    // --- prepare V for step t+1 (off-chain: depends only on x row t+1)
    {
        float xr = raw[rs];                       // row t+1
        int tn = t + 9; if (tn > TT - 1) tn = TT - 1;
        raw[rs] = xbase[(size_t)tn * (BB * 5)];   // prefetch row t+9
        float e = __expf(xr);                     // lanes 0..4 hold exp(x[t+1][b][f])
        int ei = __float_as_int(e);
#pragma unroll
        for (int i = 0; i < 8; ++i)
            Vn[i] = __int_as_float(__builtin_amdgcn_ds_bpermute(idx[i], ei));
        Sn = __int_as_float(__builtin_amdgcn_ds_bpermute(4 * 4, ei));
    }

    // --- exponent alignment: only ever scale DOWN (no overflow possible)
    int delta = Ml - M;
    if (delta > 0) {                              // neighbor frame is higher
#pragma unroll
        for (int i = 0; i < 8; ++i) F[i] = ldexpf(F[i], -delta);
        M = Ml;
        delta = 0;
    }
    const float adj = ldexpf(Fl, delta);          // delta <= 0

    // --- the recurrence (descending overwrite is safe)
#pragma unroll
    for (int i = 7; i >= 1; --i)
        F[i] = fmaf(F[i], Sc, F[i - 1] * Vc[i]);
    F[0] = fmaf(F[0], Sc, adj * Vc[0]);
    F0 *= Sc;                                     // position 0: pure stay

    // --- renorm every 8 steps
    if (renorm) {
        float m = F[0];
#pragma unroll
        for (int i = 1; i < 8; ++i) m = fmaxf(m, F[i]);
        int e2 = ((__float_as_int(m) >> 23) & 0xFF) - 127;
        e2 = (m > 0.0f) ? e2 : 0;
#pragma unroll
        for (int i = 0; i < 8; ++i) F[i] = ldexpf(F[i], -e2);
        M += e2;
        int e0 = ((__float_as_int(F0) >> 23) & 0xFF) - 127;
        e0 = (F0 > 0.0f) ? e0 : 0;
        F0 = ldexpf(F0, -e0);
        M0 += e0;
    }
}

__global__ __launch_bounds__(64, 1)
void ctc_scan(const float* __restrict__ x, const int* __restrict__ seqs,
              const int* __restrict__ seqlens, float* __restrict__ out) {
    __shared__ float garr[PP + 1];

    const int b = blockIdx.x;
    const int l = threadIdx.x;                    // 0..63

    const int f = (l < 5) ? l : 4;                // feature this lane loads
    const float* xbase = x + (size_t)b * 5 + f;   // advance by 320 floats per t

    // bpermute byte-indices: position 8l+1+i moves with feature seqs[b][8l+i]
    int idx[8];
#pragma unroll
    for (int i = 0; i < 8; ++i)
        idx[i] = seqs[b * PP + 8 * l + i] << 2;

    float F[8];
#pragma unroll
    for (int i = 0; i < 8; ++i) F[i] = 0.0f;
    float F0 = (l == 0) ? 1.0f : 0.0f;
    int M = 0, M0 = 0;

    // raw x ring: raw[r&7] holds row r, r in [t+1, t+8]
    float raw[8];
#pragma unroll
    for (int r = 1; r <= 8; ++r)
        raw[r & 7] = xbase[(size_t)r * (BB * 5)];

    // V for t=0
    float Va[8], Vb[8], Sa, Sb;
    {
        float e = __expf(xbase[0]);
        int ei = __float_as_int(e);
#pragma unroll
        for (int i = 0; i < 8; ++i)
            Va[i] = __int_as_float(__builtin_amdgcn_ds_bpermute(idx[i], ei));
        Sa = __int_as_float(__builtin_amdgcn_ds_bpermute(4 * 4, ei));
    }

    for (int tb = 0; tb < TT; tb += 8) {
        step_fn(tb + 0, 1, l, xbase, raw, idx, F, F0, M, M0, Va, Sa, Vb, Sb, false);
        step_fn(tb + 1, 2, l, xbase, raw, idx, F, F0, M, M0, Vb, Sb, Va, Sa, false);
        step_fn(tb + 2, 3, l, xbase, raw, idx, F, F0, M, M0, Va, Sa, Vb, Sb, false);
        step_fn(tb + 3, 4, l, xbase, raw, idx, F, F0, M, M0, Vb, Sb, Va, Sa, false);
        step_fn(tb + 4, 5, l, xbase, raw, idx, F, F0, M, M0, Va, Sa, Vb, Sb, false);
        step_fn(tb + 5, 6, l, xbase, raw, idx, F, F0, M, M0, Vb, Sb, Va, Sa, false);
        step_fn(tb + 6, 7, l, xbase, raw, idx, F, F0, M, M0, Va, Sa, Vb, Sb, false);
        step_fn(tb + 7, 0, l, xbase, raw, idx, F, F0, M, M0, Vb, Sb, Va, Sa, true);
    }

    // epilogue: reconstruct log2 values (denormal-safe: scale by 2^24 first)
#pragma unroll
    for (int i = 0; i < 8; ++i) {
        float v = fmaxf(F[i] * 16777216.0f, 1e-38f);
        garr[8 * l + 1 + i] = __log2f(v) - 24.0f + (float)M;
    }
    if (l == 0) {
        float v0 = fmaxf(F0 * 16777216.0f, 1e-38f);
        garr[0] = __log2f(v0) - 24.0f + (float)M0;
    }
    __syncthreads();
    if (l == 0) {
        int sl = seqlens[b];
        out[b] = -(garr[sl] * LN2F) / (float)TT;
    }
}

extern "C" void kernel_launch(void* const* d_in, const int* in_sizes, int n_in,
                              void* d_out, int out_size, void* d_ws, size_t ws_size,
                              hipStream_t stream) {
    const float* x       = (const float*)d_in[0];
    const int*   seqs    = (const int*)d_in[1];
    const int*   seqlens = (const int*)d_in[2];
    float*       out     = (float*)d_out;

    ctc_scan<<<BB, 64, 0, stream>>>(x, seqs, seqlens, out);
}